// Round 14
// baseline (539.754 us; speedup 1.0000x reference)
//
#include <hip/hip_runtime.h>
#include <hip/hip_bf16.h>

#define EPS 1e-5f

typedef __attribute__((ext_vector_type(8))) short bf16x8;
typedef __attribute__((ext_vector_type(4))) float f32x4;

// ---------------------------------------------------------------- utilities
__device__ __forceinline__ unsigned int fkey(float f) {
    unsigned int b = __float_as_uint(f);
    return (b & 0x80000000u) ? ~b : (b | 0x80000000u);
}
__device__ __forceinline__ float funkey(unsigned int k) {
    unsigned int b = (k & 0x80000000u) ? (k & 0x7fffffffu) : ~k;
    return __uint_as_float(b);
}
__device__ __forceinline__ unsigned short f2bu(float f) {
    union { __hip_bfloat16 h; unsigned short u; } cv;
    cv.h = __float2bfloat16(f);
    return cv.u;
}
__device__ __forceinline__ float bu2f(unsigned short u) {
    return __uint_as_float(((unsigned int)u) << 16);
}
__device__ __forceinline__ void hilo(float v, unsigned short& h, unsigned short& l) {
    h = f2bu(v);
    l = f2bu(v - bu2f(h));
}

// ------------------------------------------------------------ weight fragment packing (hi+lo planes)
__global__ void wfrag_kernel(const float* __restrict__ W, int CO, int C2, int C2P,
                             unsigned short* __restrict__ Fh, unsigned short* __restrict__ Fl) {
    int id = blockIdx.x * 256 + threadIdx.x;
    int total = CO * C2P;
    if (id >= total) return;
    int j = id & 7, lane = (id >> 3) & 63, t = id >> 9;
    int KS = C2P >> 5;
    int ks = t % KS, ot = t / KS;
    int o = ot * 16 + (lane & 15);
    int c = ks * 32 + ((lane >> 4) << 3) + j;
    float v = (c < C2) ? W[o * C2 + c] : 0.f;
    unsigned short h, l;
    hilo(v, h, l);
    Fh[id] = h;
    Fl[id] = l;
}

// ------------------------------------------------------------ feature fragment packing for gram MFMA
__global__ void xfrag_kernel(const float* __restrict__ feat, int fs, int C, int KS,
                             unsigned short* __restrict__ Fh, unsigned short* __restrict__ Fl) {
    const int N = 2048, NT = 128;
    int id = blockIdx.x * 256 + threadIdx.x;
    int total = 8 * NT * KS * 512;
    if (id >= total) return;
    int j = id & 7, lane = (id >> 3) & 63;
    int rest = id >> 9;
    int ks = rest % KS;
    int bt = rest / KS;
    int t = bt & 127, b = bt >> 7;
    int row = t * 16 + (lane & 15);
    int c = ks * 32 + ((lane >> 4) << 3) + j;
    float v = (c < C) ? feat[((size_t)(b * N + row)) * fs + c] : 0.f;
    unsigned short h, l;
    hilo(v, h, l);
    Fh[id] = h;
    Fl[id] = l;
}

// ------------------------------------------------------------ xx[b][n] = sum_c x^2 (row-major feat)
__global__ void sumsq_feat_kernel(const float* __restrict__ feat, int fs, int C,
                                  float* __restrict__ xx) {
    int id = blockIdx.x * 256 + threadIdx.x;
    if (id >= 8 * 2048) return;
    const float* p = feat + (size_t)id * fs;
    float s = 0.f;
    if ((C & 3) == 0) {
        for (int c = 0; c < C; c += 4) {
            float4 v = *(const float4*)(p + c);
            s = fmaf(v.x, v.x, s); s = fmaf(v.y, v.y, s);
            s = fmaf(v.z, v.z, s); s = fmaf(v.w, v.w, s);
        }
    } else {
        for (int c = 0; c < C; ++c) { float v = p[c]; s = fmaf(v, v, s); }
    }
    xx[id] = s;
}

// ------------------------------------------------------------ MFMA gram dist + exact top-20
// CAP=448 grows LDS to ~61.5 KB -> exactly 2 blocks/CU -> allocator budget 128 VGPR
// (4 waves/SIMD) -> A-fragments stay RESIDENT (round-13 spilled at 64-VGPR budget:
// 60 MB scratch writes/dispatch). Same two-sweep exact algorithm otherwise.
template <int CP>
__global__ __launch_bounds__(512, 4) void
dist_topk_mfma(const unsigned short* __restrict__ Fh, const unsigned short* __restrict__ Fl,
               const float* __restrict__ xx, int* __restrict__ idxOut) {
    const int N = 2048, NT = 128, CAP = 448;
    constexpr int KS = CP / 32;
    int b  = blockIdx.x & 7;
    int mt = blockIdx.x >> 3;
    int tid = threadIdx.x, lane = tid & 63, wv = tid >> 6;

    __shared__ unsigned int gmax[16][64];            // 4 KB
    __shared__ unsigned int Tsh[16];
    __shared__ unsigned int cnt[16];
    __shared__ unsigned long long cand[16][CAP];     // 56 KB

    // A fragments (query rows), resident
    bf16x8 Ah[KS], Al[KS];
#pragma unroll
    for (int ks = 0; ks < KS; ++ks) {
        size_t fi = (((size_t)(b * NT + mt) * KS + ks) << 9) + (lane << 3);
        Ah[ks] = *(const bf16x8*)(Fh + fi);
        Al[ks] = *(const bf16x8*)(Fl + fi);
    }
    int rbase = (lane >> 4) << 2;   // C/D row stratum
    float xxr[4];
#pragma unroll
    for (int rr = 0; rr < 4; ++rr) xxr[rr] = xx[b * N + mt * 16 + rbase + rr];

    // ---------------- sweep 1: running partition maxima (wave, half, residue&3)
    unsigned int rmax[2][4];
#pragma unroll
    for (int h = 0; h < 2; ++h)
#pragma unroll
        for (int rr = 0; rr < 4; ++rr) rmax[h][rr] = 0u;

    for (int i = 0; i < 16; ++i) {
        int ct = wv * 16 + i;
        f32x4 acc;
#pragma unroll
        for (int rr = 0; rr < 4; ++rr) acc[rr] = 0.f;
#pragma unroll
        for (int ks = 0; ks < KS; ++ks) {
            size_t fi = (((size_t)(b * NT + ct) * KS + ks) << 9) + (lane << 3);
            bf16x8 Bh = *(const bf16x8*)(Fh + fi);
            bf16x8 Bl = *(const bf16x8*)(Fl + fi);
            acc = __builtin_amdgcn_mfma_f32_16x16x32_bf16(Al[ks], Bh, acc, 0, 0, 0);
            acc = __builtin_amdgcn_mfma_f32_16x16x32_bf16(Ah[ks], Bl, acc, 0, 0, 0);
            acc = __builtin_amdgcn_mfma_f32_16x16x32_bf16(Ah[ks], Bh, acc, 0, 0, 0);
        }
        int m = ct * 16 + (lane & 15);
        float xxm = xx[b * N + m];
        int h = i >> 3;
#pragma unroll
        for (int rr = 0; rr < 4; ++rr) {
            unsigned int k = fkey(2.f * acc[rr] - xxr[rr] - xxm);
            rmax[h][rr] = rmax[h][rr] > k ? rmax[h][rr] : k;
        }
    }
#pragma unroll
    for (int s = 4; s <= 8; s <<= 1)
#pragma unroll
        for (int h = 0; h < 2; ++h)
#pragma unroll
            for (int rr = 0; rr < 4; ++rr) {
                unsigned int o = (unsigned int)__shfl_xor((int)rmax[h][rr], s);
                rmax[h][rr] = rmax[h][rr] > o ? rmax[h][rr] : o;
            }
    if ((lane & 15) < 4) {
#pragma unroll
        for (int h = 0; h < 2; ++h)
#pragma unroll
            for (int rr = 0; rr < 4; ++rr)
                gmax[rbase + rr][wv * 8 + h * 4 + (lane & 3)] = rmax[h][rr];
    }
    __syncthreads();

    // ---------------- threshold: wave sorts 64 partition maxima per row (2 rows per wave)
#pragma unroll
    for (int pass = 0; pass < 2; ++pass) {
        int row = wv + 8 * pass;
        unsigned int S = gmax[row][lane];
#pragma unroll
        for (int k = 2; k <= 64; k <<= 1)
#pragma unroll
            for (int j2 = k >> 1; j2 > 0; j2 >>= 1) {
                unsigned int o = (unsigned int)__shfl_xor((int)S, j2);
                bool keepMax = (((lane & j2) == 0) == ((lane & k) == 0));
                unsigned int mx = S > o ? S : o;
                unsigned int mn = S > o ? o : S;
                S = keepMax ? mx : mn;
            }
        if (lane == 19) Tsh[row] = S;
        if (lane == 0) cnt[row] = 0u;
    }
    __syncthreads();

    // ---------------- sweep 2: recompute (bit-identical), compact candidates >= T
    for (int i = 0; i < 16; ++i) {
        int ct = wv * 16 + i;
        f32x4 acc;
#pragma unroll
        for (int rr = 0; rr < 4; ++rr) acc[rr] = 0.f;
#pragma unroll
        for (int ks = 0; ks < KS; ++ks) {
            size_t fi = (((size_t)(b * NT + ct) * KS + ks) << 9) + (lane << 3);
            bf16x8 Bh = *(const bf16x8*)(Fh + fi);
            bf16x8 Bl = *(const bf16x8*)(Fl + fi);
            acc = __builtin_amdgcn_mfma_f32_16x16x32_bf16(Al[ks], Bh, acc, 0, 0, 0);
            acc = __builtin_amdgcn_mfma_f32_16x16x32_bf16(Ah[ks], Bl, acc, 0, 0, 0);
            acc = __builtin_amdgcn_mfma_f32_16x16x32_bf16(Ah[ks], Bh, acc, 0, 0, 0);
        }
        int m = ct * 16 + (lane & 15);
        float xxm = xx[b * N + m];
#pragma unroll
        for (int rr = 0; rr < 4; ++rr) {
            unsigned int k = fkey(2.f * acc[rr] - xxr[rr] - xxm);
            int row = rbase + rr;
            if (k >= Tsh[row]) {
                unsigned int slot = atomicAdd(&cnt[row], 1u);
                if (slot < CAP)
                    cand[row][slot] = ((unsigned long long)k << 16) |
                                      (unsigned long long)(0xFFFFu - (unsigned int)m);
            }
        }
    }
    __syncthreads();

    // ---------------- exact ordering: wave handles rows wv and wv+8
#pragma unroll
    for (int pass = 0; pass < 2; ++pass) {
        int row = wv + 8 * pass;
        unsigned int nc = cnt[row];
        if (nc <= 64u) {
            unsigned long long P = (lane < (int)nc) ? cand[row][lane] : 0ULL;
#pragma unroll
            for (int k = 2; k <= 64; k <<= 1)
#pragma unroll
                for (int j2 = k >> 1; j2 > 0; j2 >>= 1) {
                    unsigned long long o = __shfl_xor(P, j2);
                    bool keepMax = (((lane & j2) == 0) == ((lane & k) == 0));
                    unsigned long long mx = P > o ? P : o;
                    unsigned long long mn = P > o ? o : P;
                    P = keepMax ? mx : mn;
                }
            if (lane < 20)
                idxOut[((size_t)b * N + mt * 16 + row) * 20 + lane] =
                    (int)(0xFFFFu - (unsigned int)(P & 0xFFFFu));
        } else {
            unsigned int ncc = nc < CAP ? nc : CAP;
            unsigned long long P[7];
#pragma unroll
            for (int q = 0; q < 7; ++q)
                P[q] = ((unsigned int)(lane + 64 * q) < ncc) ? cand[row][lane + 64 * q] : 0ULL;
            int resm = 0;
            for (int k = 0; k < 20; ++k) {
                unsigned long long lmx = P[0];
#pragma unroll
                for (int q = 1; q < 7; ++q) lmx = lmx > P[q] ? lmx : P[q];
#pragma unroll
                for (int s = 1; s < 64; s <<= 1) {
                    unsigned long long o = __shfl_xor(lmx, s);
                    lmx = lmx > o ? lmx : o;
                }
#pragma unroll
                for (int q = 0; q < 7; ++q) P[q] = (P[q] == lmx) ? 0ULL : P[q];
                if (lane == k) resm = (int)(0xFFFFu - (unsigned int)(lmx & 0xFFFFu));
            }
            if (lane < 20) idxOut[((size_t)b * N + mt * 16 + row) * 20 + lane] = resm;
        }
    }
}

// ------------------------------------------------------------ MFMA edgeconv, hi/lo split (3 MFMA per product)
template <int CI, int CO, int TN, int WAVES, int NKC>
__global__ __launch_bounds__(WAVES * 64) void
edgeconv_mfma(const float* __restrict__ feat, int fs, const int* __restrict__ idx,
              const unsigned short* __restrict__ Wh, const unsigned short* __restrict__ Wl,
              const float* __restrict__ gp, const float* __restrict__ bp,
              const float* __restrict__ mp, const float* __restrict__ vp,
              float* __restrict__ outBase) {
    constexpr int N = 2048, K = 20;
    constexpr int C2 = 2 * CI;
    constexpr int C2P = (C2 < 32) ? 32 : C2;
    constexpr int KS = C2P / 32;
    constexpr int KSC = KS / NKC;
    constexpr int CCOLS = KSC * 32;
    constexpr int CHB = CCOLS * 2;
    constexpr int OT = CO / 16;
    constexpr int OTW = OT / WAVES;
    constexpr int M = TN * K;
    constexpr int MT = M / 16;
    constexpr int CH = CCOLS / 8;
    constexpr int SWZ = (CHB >= 128) ? 7 : (CHB / 16 - 1);
    constexpr int THREADS = WAVES * 64;

    int b  = blockIdx.x & 7;
    int n0 = (blockIdx.x >> 3) * TN;
    int tid = threadIdx.x;
    int lane = tid & 63, wv = tid >> 6;

    __shared__ float ctr[TN][CI];
    __shared__ int nb[M];
    __shared__ __align__(16) unsigned char Eh[M * CHB];
    __shared__ __align__(16) unsigned char El[M * CHB];

    for (int e = tid; e < TN * CI; e += THREADS) {
        int ln = e / CI, c = e % CI;
        ctr[ln][c] = feat[((size_t)b * N + n0 + ln) * fs + c];
    }
    for (int e = tid; e < M; e += THREADS) {
        int k = e / TN, ln = e % TN;
        nb[e] = idx[((size_t)b * N + n0 + ln) * K + k];
    }
    __syncthreads();

    f32x4 acc[MT][OTW];
#pragma unroll
    for (int mt = 0; mt < MT; ++mt)
#pragma unroll
        for (int ot = 0; ot < OTW; ++ot)
#pragma unroll
            for (int rr = 0; rr < 4; ++rr) acc[mt][ot][rr] = 0.f;

    for (int kc = 0; kc < NKC; ++kc) {
        if (kc) __syncthreads();
        for (int e = tid; e < M * CH; e += THREADS) {
            int mrow = e / CH, ch = e - mrow * CH;
            int c0 = kc * CCOLS + ch * 8;
            int ln = mrow % TN;
            float v[8];
            if constexpr (CI >= 8) {
                if (c0 < CI) {
#pragma unroll
                    for (int j = 0; j < 8; ++j) v[j] = ctr[ln][c0 + j];
                } else {
                    int c1 = c0 - CI;
                    const float* nrow = feat + ((size_t)b * N + nb[mrow]) * fs + c1;
                    float4 a  = *(const float4*)nrow;
                    float4 b4 = *(const float4*)(nrow + 4);
                    v[0] = a.x  - ctr[ln][c1 + 0];
                    v[1] = a.y  - ctr[ln][c1 + 1];
                    v[2] = a.z  - ctr[ln][c1 + 2];
                    v[3] = a.w  - ctr[ln][c1 + 3];
                    v[4] = b4.x - ctr[ln][c1 + 4];
                    v[5] = b4.y - ctr[ln][c1 + 5];
                    v[6] = b4.z - ctr[ln][c1 + 6];
                    v[7] = b4.w - ctr[ln][c1 + 7];
                }
            } else {
                if (c0 == 0) {
                    const float* nrow = feat + ((size_t)b * N + nb[mrow]) * fs;
                    v[0] = ctr[ln][0]; v[1] = ctr[ln][1]; v[2] = ctr[ln][2];
                    v[3] = nrow[0] - ctr[ln][0];
                    v[4] = nrow[1] - ctr[ln][1];
                    v[5] = nrow[2] - ctr[ln][2];
                    v[6] = 0.f; v[7] = 0.f;
                } else {
#pragma unroll
                    for (int j = 0; j < 8; ++j) v[j] = 0.f;
                }
            }
            union { unsigned short u[8]; uint4 v4; } th, tl;
#pragma unroll
            for (int j = 0; j < 8; ++j) hilo(v[j], th.u[j], tl.u[j]);
            int off = mrow * CHB + ((ch * 16) ^ ((mrow & SWZ) << 4));
            *(uint4*)&Eh[off] = th.v4;
            *(uint4*)&El[off] = tl.v4;
        }
        __syncthreads();

        bf16x8 Bh[OTW][KSC], Bl[OTW][KSC];
#pragma unroll
        for (int ot = 0; ot < OTW; ++ot)
#pragma unroll
            for (int ksc = 0; ksc < KSC; ++ksc) {
                size_t fi = (size_t)((((wv * OTW + ot) * KS + kc * KSC + ksc) * 64 + lane)) << 3;
                Bh[ot][ksc] = *(const bf16x8*)(Wh + fi);
                Bl[ot][ksc] = *(const bf16x8*)(Wl + fi);
            }

#pragma unroll
        for (int mt = 0; mt < MT; ++mt) {
            int r0 = mt * 16 + (lane & 15);
            int cb = (lane >> 4) << 4;
            bf16x8 Ah[KSC], Al[KSC];
#pragma unroll
            for (int ksc = 0; ksc < KSC; ++ksc) {
                int off = r0 * CHB + (((ksc << 6) + cb) ^ ((r0 & SWZ) << 4));
                Ah[ksc] = *(const bf16x8*)&Eh[off];
                Al[ksc] = *(const bf16x8*)&El[off];
            }
#pragma unroll
            for (int ksc = 0; ksc < KSC; ++ksc)
#pragma unroll
                for (int ot = 0; ot < OTW; ++ot) {
                    acc[mt][ot] = __builtin_amdgcn_mfma_f32_16x16x32_bf16(Al[ksc], Bh[ot][ksc], acc[mt][ot], 0, 0, 0);
                    acc[mt][ot] = __builtin_amdgcn_mfma_f32_16x16x32_bf16(Ah[ksc], Bl[ot][ksc], acc[mt][ot], 0, 0, 0);
                    acc[mt][ot] = __builtin_amdgcn_mfma_f32_16x16x32_bf16(Ah[ksc], Bh[ot][ksc], acc[mt][ot], 0, 0, 0);
                }
        }
    }

#pragma unroll
    for (int ot = 0; ot < OTW; ++ot) {
        f32x4 v;
#pragma unroll
        for (int rr = 0; rr < 4; ++rr) {
            float m = acc[0][ot][rr];
#pragma unroll
            for (int mt = 1; mt < MT; ++mt) m = fmaxf(m, acc[mt][ot][rr]);
            if constexpr (TN == 4) m = fmaxf(m, __shfl_xor(m, 16));
            m = fmaxf(m, __shfl_xor(m, 32));
            v[rr] = m;
        }
        int o = (wv * OTW + ot) * 16 + (lane & 15);
        float s  = gp[o] * rsqrtf(vp[o] + EPS);
        float sh = bp[o] - mp[o] * s;
        bool valid = (TN == 8) ? (lane < 32) : (lane < 16);
        if (valid) {
            int lnb = (TN == 8) ? ((lane >> 4) << 2) : 0;
#pragma unroll
            for (int rr = 0; rr < 4; ++rr) {
                float h = fmaf(v[rr], s, sh);
                h = h > 0.f ? h : 0.2f * h;
                outBase[((size_t)b * N + n0 + lnb + rr) * 512 + o] = h;
            }
        }
    }
}

// ------------------------------------------------------------ global 512x512 MFMA (hi/lo), streaming K-loop
__global__ __launch_bounds__(256) void
global_mfma(const float* __restrict__ xcat,
            const unsigned short* __restrict__ Wh, const unsigned short* __restrict__ Wl,
            const float* __restrict__ gg, const float* __restrict__ bg,
            const float* __restrict__ mg, const float* __restrict__ vg,
            unsigned int* __restrict__ keys) {
    const int N = 2048, CV = 512;
    int b     = blockIdx.x & 7;
    int t     = blockIdx.x >> 3;
    int n0    = (t & 63) * 32;
    int colh  = t >> 6;
    int tid = threadIdx.x, lane = tid & 63, wv = tid >> 6;
    int obase = colh * 16 + wv * 4;

    f32x4 acc0[4], acc1[4];
#pragma unroll
    for (int ot = 0; ot < 4; ++ot)
#pragma unroll
        for (int rr = 0; rr < 4; ++rr) { acc0[ot][rr] = 0.f; acc1[ot][rr] = 0.f; }

    const float* arow0 = xcat + ((size_t)b * N + n0 +      (lane & 15)) * CV + ((lane >> 4) << 3);
    const float* arow1 = xcat + ((size_t)b * N + n0 + 16 + (lane & 15)) * CV + ((lane >> 4) << 3);

    for (int ks = 0; ks < 16; ++ks) {
        bf16x8 Ah0, Al0, Ah1, Al1;
        {
            float4 a  = *(const float4*)(arow0 + ks * 32);
            float4 b4 = *(const float4*)(arow0 + ks * 32 + 4);
            union { unsigned short u[8]; bf16x8 v; } ch, cl;
            hilo(a.x,  ch.u[0], cl.u[0]); hilo(a.y,  ch.u[1], cl.u[1]);
            hilo(a.z,  ch.u[2], cl.u[2]); hilo(a.w,  ch.u[3], cl.u[3]);
            hilo(b4.x, ch.u[4], cl.u[4]); hilo(b4.y, ch.u[5], cl.u[5]);
            hilo(b4.z, ch.u[6], cl.u[6]); hilo(b4.w, ch.u[7], cl.u[7]);
            Ah0 = ch.v; Al0 = cl.v;
        }
        {
            float4 a  = *(const float4*)(arow1 + ks * 32);
            float4 b4 = *(const float4*)(arow1 + ks * 32 + 4);
            union { unsigned short u[8]; bf16x8 v; } ch, cl;
            hilo(a.x,  ch.u[0], cl.u[0]); hilo(a.y,  ch.u[1], cl.u[1]);
            hilo(a.z,  ch.u[2], cl.u[2]); hilo(a.w,  ch.u[3], cl.u[3]);
            hilo(b4.x, ch.u[4], cl.u[4]); hilo(b4.y, ch.u[5], cl.u[5]);
            hilo(b4.z, ch.u[6], cl.u[6]); hilo(b4.w, ch.u[7], cl.u[7]);
            Ah1 = ch.v; Al1 = cl.v;
        }
#pragma unroll
        for (int ot = 0; ot < 4; ++ot) {
            size_t fi = (size_t)((((obase + ot) * 16 + ks) * 64 + lane)) << 3;
            bf16x8 Bh = *(const bf16x8*)(Wh + fi);
            bf16x8 Bl = *(const bf16x8*)(Wl + fi);
            acc0[ot] = __builtin_amdgcn_mfma_f32_16x16x32_bf16(Al0, Bh, acc0[ot], 0, 0, 0);
            acc0[ot] = __builtin_amdgcn_mfma_f32_16x16x32_bf16(Ah0, Bl, acc0[ot], 0, 0, 0);
            acc0[ot] = __builtin_amdgcn_mfma_f32_16x16x32_bf16(Ah0, Bh, acc0[ot], 0, 0, 0);
            acc1[ot] = __builtin_amdgcn_mfma_f32_16x16x32_bf16(Al1, Bh, acc1[ot], 0, 0, 0);
            acc1[ot] = __builtin_amdgcn_mfma_f32_16x16x32_bf16(Ah1, Bl, acc1[ot], 0, 0, 0);
            acc1[ot] = __builtin_amdgcn_mfma_f32_16x16x32_bf16(Ah1, Bh, acc1[ot], 0, 0, 0);
        }
    }

#pragma unroll
    for (int ot = 0; ot < 4; ++ot) {
        f32x4 v;
#pragma unroll
        for (int rr = 0; rr < 4; ++rr) {
            float m = fmaxf(acc0[ot][rr], acc1[ot][rr]);
            m = fmaxf(m, __shfl_xor(m, 16));
            m = fmaxf(m, __shfl_xor(m, 32));
            v[rr] = m;
        }
        int o = (obase + ot) * 16 + (lane & 15);
        float s  = gg[o] * rsqrtf(vg[o] + EPS);
        float sh = bg[o] - mg[o] * s;
        if (lane < 16) {
            float hm = -INFINITY;
#pragma unroll
            for (int rr = 0; rr < 4; ++rr) {
                float h = fmaf(v[rr], s, sh);
                h = h > 0.f ? h : 0.2f * h;
                hm = fmaxf(hm, h);
            }
            atomicMax(&keys[b * 512 + o], fkey(hm));
        }
    }
}

__global__ void decode_kernel(const unsigned int* __restrict__ keys, float* __restrict__ out) {
    int id = blockIdx.x * 256 + threadIdx.x;
    if (id < 8 * 512) out[id] = funkey(keys[id]);
}

// ---------------------------------------------------------------- launcher
extern "C" void kernel_launch(void* const* d_in, const int* in_sizes, int n_in,
                              void* d_out, int out_size, void* d_ws, size_t ws_size,
                              hipStream_t stream) {
    const int B = 8, N = 2048, K = 20;
    const float* pts = (const float*)d_in[0];
    const float* w1 = (const float*)d_in[1];
    const float *g1 = (const float*)d_in[2], *b1 = (const float*)d_in[3],
                *m1 = (const float*)d_in[4], *v1 = (const float*)d_in[5];
    const float* w2 = (const float*)d_in[6];
    const float *g2 = (const float*)d_in[7], *b2 = (const float*)d_in[8],
                *m2 = (const float*)d_in[9], *v2 = (const float*)d_in[10];
    const float* w3 = (const float*)d_in[11];
    const float *g3 = (const float*)d_in[12], *b3 = (const float*)d_in[13],
                *m3 = (const float*)d_in[14], *v3 = (const float*)d_in[15];
    const float* w4 = (const float*)d_in[16];
    const float *g4 = (const float*)d_in[17], *b4 = (const float*)d_in[18],
                *m4 = (const float*)d_in[19], *v4 = (const float*)d_in[20];
    const float* wg = (const float*)d_in[21];
    const float *gg = (const float*)d_in[22], *bg = (const float*)d_in[23],
                *mg = (const float*)d_in[24], *vg = (const float*)d_in[25];

    // workspace layout
    float* ws   = (float*)d_ws;
    float* xcat = ws;                                    // 8*2048*512 floats
    float* xx   = xcat + (size_t)B * N * 512;            // 8*2048
    int*   idx  = (int*)(xx + B * N);                    // 8*2048*20
    unsigned short* Fdh = (unsigned short*)(idx + (size_t)B * N * K);  // 8*2048*128 max
    unsigned short* Fdl = Fdh + (size_t)B * N * 128;
    unsigned short* wf1h = Fdl + (size_t)B * N * 128;
    unsigned short* wf1l = wf1h + 64 * 32;
    unsigned short* wf2h = wf1l + 64 * 32;
    unsigned short* wf2l = wf2h + 64 * 128;
    unsigned short* wf3h = wf2l + 64 * 128;
    unsigned short* wf3l = wf3h + 128 * 128;
    unsigned short* wf4h = wf3l + 128 * 128;
    unsigned short* wf4l = wf4h + 256 * 256;
    unsigned short* wfgh = wf4l + 256 * 256;
    unsigned short* wfgl = wfgh + 512 * 512;
    unsigned int* keys  = (unsigned int*)(wfgl + 512 * 512);

    // pack weight fragments (bf16 hi/lo)
    wfrag_kernel<<<(64 * 32 + 255) / 256, 256, 0, stream>>>(w1, 64, 6, 32, wf1h, wf1l);
    wfrag_kernel<<<(64 * 128 + 255) / 256, 256, 0, stream>>>(w2, 64, 128, 128, wf2h, wf2l);
    wfrag_kernel<<<(128 * 128 + 255) / 256, 256, 0, stream>>>(w3, 128, 128, 128, wf3h, wf3l);
    wfrag_kernel<<<(256 * 256 + 255) / 256, 256, 0, stream>>>(w4, 256, 256, 256, wf4h, wf4l);
    wfrag_kernel<<<(512 * 512 + 255) / 256, 256, 0, stream>>>(wg, 512, 512, 512, wfgh, wfgl);

    // ---- layer 1: C=3 -> 64, out offset 0
    xfrag_kernel<<<(8 * 128 * 1 * 512 + 255) / 256, 256, 0, stream>>>(pts, 3, 3, 1, Fdh, Fdl);
    sumsq_feat_kernel<<<(B * N + 255) / 256, 256, 0, stream>>>(pts, 3, 3, xx);
    dist_topk_mfma<32><<<B * (N / 16), 512, 0, stream>>>(Fdh, Fdl, xx, idx);
    edgeconv_mfma<3, 64, 8, 4, 1><<<B * (N / 8), 256, 0, stream>>>(pts, 3, idx, wf1h, wf1l, g1, b1, m1, v1, xcat + 0);

    // ---- layer 2: 64 -> 64, out offset 64
    xfrag_kernel<<<(8 * 128 * 2 * 512 + 255) / 256, 256, 0, stream>>>(xcat + 0, 512, 64, 2, Fdh, Fdl);
    sumsq_feat_kernel<<<(B * N + 255) / 256, 256, 0, stream>>>(xcat + 0, 512, 64, xx);
    dist_topk_mfma<64><<<B * (N / 16), 512, 0, stream>>>(Fdh, Fdl, xx, idx);
    edgeconv_mfma<64, 64, 4, 4, 1><<<B * (N / 4), 256, 0, stream>>>(xcat + 0, 512, idx, wf2h, wf2l, g2, b2, m2, v2, xcat + 64);

    // ---- layer 3: 64 -> 128, out offset 128
    xfrag_kernel<<<(8 * 128 * 2 * 512 + 255) / 256, 256, 0, stream>>>(xcat + 64, 512, 64, 2, Fdh, Fdl);
    sumsq_feat_kernel<<<(B * N + 255) / 256, 256, 0, stream>>>(xcat + 64, 512, 64, xx);
    dist_topk_mfma<64><<<B * (N / 16), 512, 0, stream>>>(Fdh, Fdl, xx, idx);
    edgeconv_mfma<64, 128, 4, 8, 1><<<B * (N / 4), 512, 0, stream>>>(xcat + 64, 512, idx, wf3h, wf3l, g3, b3, m3, v3, xcat + 128);

    // ---- layer 4: 128 -> 256, out offset 256 (K-chunked: NKC=2)
    xfrag_kernel<<<(8 * 128 * 4 * 512 + 255) / 256, 256, 0, stream>>>(xcat + 128, 512, 128, 4, Fdh, Fdl);
    sumsq_feat_kernel<<<(B * N + 255) / 256, 256, 0, stream>>>(xcat + 128, 512, 128, xx);
    dist_topk_mfma<128><<<B * (N / 16), 512, 0, stream>>>(Fdh, Fdl, xx, idx);
    edgeconv_mfma<128, 256, 4, 8, 2><<<B * (N / 4), 512, 0, stream>>>(xcat + 128, 512, idx, wf4h, wf4l, g4, b4, m4, v4, xcat + 256);

    // ---- global layer + max over N
    hipMemsetAsync(keys, 0, (size_t)B * 512 * sizeof(unsigned int), stream);
    global_mfma<<<B * 128, 256, 0, stream>>>(xcat, wfgh, wfgl, gg, bg, mg, vg, keys);
    decode_kernel<<<(B * 512 + 255) / 256, 256, 0, stream>>>(keys, (float*)d_out);
}

// Round 15
// 506.203 us; speedup vs baseline: 1.0663x; 1.0663x over previous
//
#include <hip/hip_runtime.h>
#include <hip/hip_bf16.h>

#define EPS 1e-5f

typedef __attribute__((ext_vector_type(8))) short bf16x8;
typedef __attribute__((ext_vector_type(4))) float f32x4;

// ---------------------------------------------------------------- utilities
__device__ __forceinline__ unsigned int fkey(float f) {
    unsigned int b = __float_as_uint(f);
    return (b & 0x80000000u) ? ~b : (b | 0x80000000u);
}
__device__ __forceinline__ float funkey(unsigned int k) {
    unsigned int b = (k & 0x80000000u) ? (k & 0x7fffffffu) : ~k;
    return __uint_as_float(b);
}
__device__ __forceinline__ unsigned short f2bu(float f) {
    union { __hip_bfloat16 h; unsigned short u; } cv;
    cv.h = __float2bfloat16(f);
    return cv.u;
}
__device__ __forceinline__ float bu2f(unsigned short u) {
    return __uint_as_float(((unsigned int)u) << 16);
}
__device__ __forceinline__ void hilo(float v, unsigned short& h, unsigned short& l) {
    h = f2bu(v);
    l = f2bu(v - bu2f(h));
}

// ------------------------------------------------------------ weight fragment packing (hi+lo planes)
__global__ void wfrag_kernel(const float* __restrict__ W, int CO, int C2, int C2P,
                             unsigned short* __restrict__ Fh, unsigned short* __restrict__ Fl) {
    int id = blockIdx.x * 256 + threadIdx.x;
    int total = CO * C2P;
    if (id >= total) return;
    int j = id & 7, lane = (id >> 3) & 63, t = id >> 9;
    int KS = C2P >> 5;
    int ks = t % KS, ot = t / KS;
    int o = ot * 16 + (lane & 15);
    int c = ks * 32 + ((lane >> 4) << 3) + j;
    float v = (c < C2) ? W[o * C2 + c] : 0.f;
    unsigned short h, l;
    hilo(v, h, l);
    Fh[id] = h;
    Fl[id] = l;
}

// ------------------------------------------------------------ feature fragment packing for gram MFMA
__global__ void xfrag_kernel(const float* __restrict__ feat, int fs, int C, int KS,
                             unsigned short* __restrict__ Fh, unsigned short* __restrict__ Fl) {
    const int N = 2048, NT = 128;
    int id = blockIdx.x * 256 + threadIdx.x;
    int total = 8 * NT * KS * 512;
    if (id >= total) return;
    int j = id & 7, lane = (id >> 3) & 63;
    int rest = id >> 9;
    int ks = rest % KS;
    int bt = rest / KS;
    int t = bt & 127, b = bt >> 7;
    int row = t * 16 + (lane & 15);
    int c = ks * 32 + ((lane >> 4) << 3) + j;
    float v = (c < C) ? feat[((size_t)(b * N + row)) * fs + c] : 0.f;
    unsigned short h, l;
    hilo(v, h, l);
    Fh[id] = h;
    Fl[id] = l;
}

// ------------------------------------------------------------ xx[b][n] = sum_c x^2 (row-major feat)
__global__ void sumsq_feat_kernel(const float* __restrict__ feat, int fs, int C,
                                  float* __restrict__ xx) {
    int id = blockIdx.x * 256 + threadIdx.x;
    if (id >= 8 * 2048) return;
    const float* p = feat + (size_t)id * fs;
    float s = 0.f;
    if ((C & 3) == 0) {
        for (int c = 0; c < C; c += 4) {
            float4 v = *(const float4*)(p + c);
            s = fmaf(v.x, v.x, s); s = fmaf(v.y, v.y, s);
            s = fmaf(v.z, v.z, s); s = fmaf(v.w, v.w, s);
        }
    } else {
        for (int c = 0; c < C; ++c) { float v = p[c]; s = fmaf(v, v, s); }
    }
    xx[id] = s;
}

// ------------------------------------------------------------ MFMA gram dist + exact top-20
// Rule-#20 fix vs r13/r14: sweep-1 maxima now live in STATICALLY-indexed arrays
// (rmax0/rmax1, two explicit half-loops) -- no runtime-indexed register arrays,
// no scratch. Same two-sweep exact algorithm otherwise.
template <int CP>
__global__ __launch_bounds__(512, 4) void
dist_topk_mfma(const unsigned short* __restrict__ Fh, const unsigned short* __restrict__ Fl,
               const float* __restrict__ xx, int* __restrict__ idxOut) {
    const int N = 2048, NT = 128, CAP = 448;
    constexpr int KS = CP / 32;
    int b  = blockIdx.x & 7;
    int mt = blockIdx.x >> 3;
    int tid = threadIdx.x, lane = tid & 63, wv = tid >> 6;

    __shared__ unsigned int gmax[16][64];            // 4 KB
    __shared__ unsigned int Tsh[16];
    __shared__ unsigned int cnt[16];
    __shared__ unsigned long long cand[16][CAP];     // 56 KB

    // A fragments (query rows), resident
    bf16x8 Ah[KS], Al[KS];
#pragma unroll
    for (int ks = 0; ks < KS; ++ks) {
        size_t fi = (((size_t)(b * NT + mt) * KS + ks) << 9) + (lane << 3);
        Ah[ks] = *(const bf16x8*)(Fh + fi);
        Al[ks] = *(const bf16x8*)(Fl + fi);
    }
    int rbase = (lane >> 4) << 2;   // C/D row stratum
    float xxr[4];
#pragma unroll
    for (int rr = 0; rr < 4; ++rr) xxr[rr] = xx[b * N + mt * 16 + rbase + rr];

    // gram tile for col-tile ct -> 4 distance keys (one per C/D row of this lane)
    auto gramkeys = [&](int ct, unsigned int* kout) {
        f32x4 acc;
#pragma unroll
        for (int rr = 0; rr < 4; ++rr) acc[rr] = 0.f;
#pragma unroll
        for (int ks = 0; ks < KS; ++ks) {
            size_t fi = (((size_t)(b * NT + ct) * KS + ks) << 9) + (lane << 3);
            bf16x8 Bh = *(const bf16x8*)(Fh + fi);
            bf16x8 Bl = *(const bf16x8*)(Fl + fi);
            acc = __builtin_amdgcn_mfma_f32_16x16x32_bf16(Al[ks], Bh, acc, 0, 0, 0);
            acc = __builtin_amdgcn_mfma_f32_16x16x32_bf16(Ah[ks], Bl, acc, 0, 0, 0);
            acc = __builtin_amdgcn_mfma_f32_16x16x32_bf16(Ah[ks], Bh, acc, 0, 0, 0);
        }
        float xxm = xx[b * N + ct * 16 + (lane & 15)];
#pragma unroll
        for (int rr = 0; rr < 4; ++rr)
            kout[rr] = fkey(2.f * acc[rr] - xxr[rr] - xxm);
    };

    // ---------------- sweep 1: running partition maxima, two STATIC halves
    unsigned int rmax0[4], rmax1[4];
#pragma unroll
    for (int rr = 0; rr < 4; ++rr) { rmax0[rr] = 0u; rmax1[rr] = 0u; }

    for (int i = 0; i < 8; ++i) {
        unsigned int kk[4];
        gramkeys(wv * 16 + i, kk);
#pragma unroll
        for (int rr = 0; rr < 4; ++rr) rmax0[rr] = rmax0[rr] > kk[rr] ? rmax0[rr] : kk[rr];
    }
    for (int i = 8; i < 16; ++i) {
        unsigned int kk[4];
        gramkeys(wv * 16 + i, kk);
#pragma unroll
        for (int rr = 0; rr < 4; ++rr) rmax1[rr] = rmax1[rr] > kk[rr] ? rmax1[rr] : kk[rr];
    }
#pragma unroll
    for (int s = 4; s <= 8; s <<= 1)
#pragma unroll
        for (int rr = 0; rr < 4; ++rr) {
            unsigned int o0 = (unsigned int)__shfl_xor((int)rmax0[rr], s);
            rmax0[rr] = rmax0[rr] > o0 ? rmax0[rr] : o0;
            unsigned int o1 = (unsigned int)__shfl_xor((int)rmax1[rr], s);
            rmax1[rr] = rmax1[rr] > o1 ? rmax1[rr] : o1;
        }
    if ((lane & 15) < 4) {
#pragma unroll
        for (int rr = 0; rr < 4; ++rr) {
            gmax[rbase + rr][wv * 8 + (lane & 3)]     = rmax0[rr];
            gmax[rbase + rr][wv * 8 + 4 + (lane & 3)] = rmax1[rr];
        }
    }
    __syncthreads();

    // ---------------- threshold: wave sorts 64 partition maxima per row (2 rows per wave)
#pragma unroll
    for (int pass = 0; pass < 2; ++pass) {
        int row = wv + 8 * pass;
        unsigned int S = gmax[row][lane];
#pragma unroll
        for (int k = 2; k <= 64; k <<= 1)
#pragma unroll
            for (int j2 = k >> 1; j2 > 0; j2 >>= 1) {
                unsigned int o = (unsigned int)__shfl_xor((int)S, j2);
                bool keepMax = (((lane & j2) == 0) == ((lane & k) == 0));
                unsigned int mx = S > o ? S : o;
                unsigned int mn = S > o ? o : S;
                S = keepMax ? mx : mn;
            }
        if (lane == 19) Tsh[row] = S;
        if (lane == 0) cnt[row] = 0u;
    }
    __syncthreads();

    // ---------------- sweep 2: recompute (bit-identical), compact candidates >= T
    for (int i = 0; i < 16; ++i) {
        int ct = wv * 16 + i;
        unsigned int kk[4];
        gramkeys(ct, kk);
        int m = ct * 16 + (lane & 15);
#pragma unroll
        for (int rr = 0; rr < 4; ++rr) {
            int row = rbase + rr;
            if (kk[rr] >= Tsh[row]) {
                unsigned int slot = atomicAdd(&cnt[row], 1u);
                if (slot < CAP)
                    cand[row][slot] = ((unsigned long long)kk[rr] << 16) |
                                      (unsigned long long)(0xFFFFu - (unsigned int)m);
            }
        }
    }
    __syncthreads();

    // ---------------- exact ordering: wave handles rows wv and wv+8
#pragma unroll
    for (int pass = 0; pass < 2; ++pass) {
        int row = wv + 8 * pass;
        unsigned int nc = cnt[row];
        if (nc <= 64u) {
            unsigned long long P = (lane < (int)nc) ? cand[row][lane] : 0ULL;
#pragma unroll
            for (int k = 2; k <= 64; k <<= 1)
#pragma unroll
                for (int j2 = k >> 1; j2 > 0; j2 >>= 1) {
                    unsigned long long o = __shfl_xor(P, j2);
                    bool keepMax = (((lane & j2) == 0) == ((lane & k) == 0));
                    unsigned long long mx = P > o ? P : o;
                    unsigned long long mn = P > o ? o : P;
                    P = keepMax ? mx : mn;
                }
            if (lane < 20)
                idxOut[((size_t)b * N + mt * 16 + row) * 20 + lane] =
                    (int)(0xFFFFu - (unsigned int)(P & 0xFFFFu));
        } else {
            unsigned int ncc = nc < CAP ? nc : CAP;
            unsigned long long P0 = ((unsigned int)(lane)       < ncc) ? cand[row][lane]       : 0ULL;
            unsigned long long P1 = ((unsigned int)(lane + 64)  < ncc) ? cand[row][lane + 64]  : 0ULL;
            unsigned long long P2 = ((unsigned int)(lane + 128) < ncc) ? cand[row][lane + 128] : 0ULL;
            unsigned long long P3 = ((unsigned int)(lane + 192) < ncc) ? cand[row][lane + 192] : 0ULL;
            unsigned long long P4 = ((unsigned int)(lane + 256) < ncc) ? cand[row][lane + 256] : 0ULL;
            unsigned long long P5 = ((unsigned int)(lane + 320) < ncc) ? cand[row][lane + 320] : 0ULL;
            unsigned long long P6 = ((unsigned int)(lane + 384) < ncc) ? cand[row][lane + 384] : 0ULL;
            int resm = 0;
            for (int k = 0; k < 20; ++k) {
                unsigned long long lmx = P0;
                lmx = lmx > P1 ? lmx : P1;
                lmx = lmx > P2 ? lmx : P2;
                lmx = lmx > P3 ? lmx : P3;
                lmx = lmx > P4 ? lmx : P4;
                lmx = lmx > P5 ? lmx : P5;
                lmx = lmx > P6 ? lmx : P6;
#pragma unroll
                for (int s = 1; s < 64; s <<= 1) {
                    unsigned long long o = __shfl_xor(lmx, s);
                    lmx = lmx > o ? lmx : o;
                }
                P0 = (P0 == lmx) ? 0ULL : P0;
                P1 = (P1 == lmx) ? 0ULL : P1;
                P2 = (P2 == lmx) ? 0ULL : P2;
                P3 = (P3 == lmx) ? 0ULL : P3;
                P4 = (P4 == lmx) ? 0ULL : P4;
                P5 = (P5 == lmx) ? 0ULL : P5;
                P6 = (P6 == lmx) ? 0ULL : P6;
                if (lane == k) resm = (int)(0xFFFFu - (unsigned int)(lmx & 0xFFFFu));
            }
            if (lane < 20) idxOut[((size_t)b * N + mt * 16 + row) * 20 + lane] = resm;
        }
    }
}

// ------------------------------------------------------------ MFMA edgeconv, hi/lo split (3 MFMA per product)
template <int CI, int CO, int TN, int WAVES, int NKC>
__global__ __launch_bounds__(WAVES * 64) void
edgeconv_mfma(const float* __restrict__ feat, int fs, const int* __restrict__ idx,
              const unsigned short* __restrict__ Wh, const unsigned short* __restrict__ Wl,
              const float* __restrict__ gp, const float* __restrict__ bp,
              const float* __restrict__ mp, const float* __restrict__ vp,
              float* __restrict__ outBase) {
    constexpr int N = 2048, K = 20;
    constexpr int C2 = 2 * CI;
    constexpr int C2P = (C2 < 32) ? 32 : C2;
    constexpr int KS = C2P / 32;
    constexpr int KSC = KS / NKC;
    constexpr int CCOLS = KSC * 32;
    constexpr int CHB = CCOLS * 2;
    constexpr int OT = CO / 16;
    constexpr int OTW = OT / WAVES;
    constexpr int M = TN * K;
    constexpr int MT = M / 16;
    constexpr int CH = CCOLS / 8;
    constexpr int SWZ = (CHB >= 128) ? 7 : (CHB / 16 - 1);
    constexpr int THREADS = WAVES * 64;

    int b  = blockIdx.x & 7;
    int n0 = (blockIdx.x >> 3) * TN;
    int tid = threadIdx.x;
    int lane = tid & 63, wv = tid >> 6;

    __shared__ float ctr[TN][CI];
    __shared__ int nb[M];
    __shared__ __align__(16) unsigned char Eh[M * CHB];
    __shared__ __align__(16) unsigned char El[M * CHB];

    for (int e = tid; e < TN * CI; e += THREADS) {
        int ln = e / CI, c = e % CI;
        ctr[ln][c] = feat[((size_t)b * N + n0 + ln) * fs + c];
    }
    for (int e = tid; e < M; e += THREADS) {
        int k = e / TN, ln = e % TN;
        nb[e] = idx[((size_t)b * N + n0 + ln) * K + k];
    }
    __syncthreads();

    f32x4 acc[MT][OTW];
#pragma unroll
    for (int mt = 0; mt < MT; ++mt)
#pragma unroll
        for (int ot = 0; ot < OTW; ++ot)
#pragma unroll
            for (int rr = 0; rr < 4; ++rr) acc[mt][ot][rr] = 0.f;

    for (int kc = 0; kc < NKC; ++kc) {
        if (kc) __syncthreads();
        for (int e = tid; e < M * CH; e += THREADS) {
            int mrow = e / CH, ch = e - mrow * CH;
            int c0 = kc * CCOLS + ch * 8;
            int ln = mrow % TN;
            float v[8];
            if constexpr (CI >= 8) {
                if (c0 < CI) {
#pragma unroll
                    for (int j = 0; j < 8; ++j) v[j] = ctr[ln][c0 + j];
                } else {
                    int c1 = c0 - CI;
                    const float* nrow = feat + ((size_t)b * N + nb[mrow]) * fs + c1;
                    float4 a  = *(const float4*)nrow;
                    float4 b4 = *(const float4*)(nrow + 4);
                    v[0] = a.x  - ctr[ln][c1 + 0];
                    v[1] = a.y  - ctr[ln][c1 + 1];
                    v[2] = a.z  - ctr[ln][c1 + 2];
                    v[3] = a.w  - ctr[ln][c1 + 3];
                    v[4] = b4.x - ctr[ln][c1 + 4];
                    v[5] = b4.y - ctr[ln][c1 + 5];
                    v[6] = b4.z - ctr[ln][c1 + 6];
                    v[7] = b4.w - ctr[ln][c1 + 7];
                }
            } else {
                if (c0 == 0) {
                    const float* nrow = feat + ((size_t)b * N + nb[mrow]) * fs;
                    v[0] = ctr[ln][0]; v[1] = ctr[ln][1]; v[2] = ctr[ln][2];
                    v[3] = nrow[0] - ctr[ln][0];
                    v[4] = nrow[1] - ctr[ln][1];
                    v[5] = nrow[2] - ctr[ln][2];
                    v[6] = 0.f; v[7] = 0.f;
                } else {
#pragma unroll
                    for (int j = 0; j < 8; ++j) v[j] = 0.f;
                }
            }
            union { unsigned short u[8]; uint4 v4; } th, tl;
#pragma unroll
            for (int j = 0; j < 8; ++j) hilo(v[j], th.u[j], tl.u[j]);
            int off = mrow * CHB + ((ch * 16) ^ ((mrow & SWZ) << 4));
            *(uint4*)&Eh[off] = th.v4;
            *(uint4*)&El[off] = tl.v4;
        }
        __syncthreads();

        bf16x8 Bh[OTW][KSC], Bl[OTW][KSC];
#pragma unroll
        for (int ot = 0; ot < OTW; ++ot)
#pragma unroll
            for (int ksc = 0; ksc < KSC; ++ksc) {
                size_t fi = (size_t)((((wv * OTW + ot) * KS + kc * KSC + ksc) * 64 + lane)) << 3;
                Bh[ot][ksc] = *(const bf16x8*)(Wh + fi);
                Bl[ot][ksc] = *(const bf16x8*)(Wl + fi);
            }

#pragma unroll
        for (int mt = 0; mt < MT; ++mt) {
            int r0 = mt * 16 + (lane & 15);
            int cb = (lane >> 4) << 4;
            bf16x8 Ah[KSC], Al[KSC];
#pragma unroll
            for (int ksc = 0; ksc < KSC; ++ksc) {
                int off = r0 * CHB + (((ksc << 6) + cb) ^ ((r0 & SWZ) << 4));
                Ah[ksc] = *(const bf16x8*)&Eh[off];
                Al[ksc] = *(const bf16x8*)&El[off];
            }
#pragma unroll
            for (int ksc = 0; ksc < KSC; ++ksc)
#pragma unroll
                for (int ot = 0; ot < OTW; ++ot) {
                    acc[mt][ot] = __builtin_amdgcn_mfma_f32_16x16x32_bf16(Al[ksc], Bh[ot][ksc], acc[mt][ot], 0, 0, 0);
                    acc[mt][ot] = __builtin_amdgcn_mfma_f32_16x16x32_bf16(Ah[ksc], Bl[ot][ksc], acc[mt][ot], 0, 0, 0);
                    acc[mt][ot] = __builtin_amdgcn_mfma_f32_16x16x32_bf16(Ah[ksc], Bh[ot][ksc], acc[mt][ot], 0, 0, 0);
                }
        }
    }

#pragma unroll
    for (int ot = 0; ot < OTW; ++ot) {
        f32x4 v;
#pragma unroll
        for (int rr = 0; rr < 4; ++rr) {
            float m = acc[0][ot][rr];
#pragma unroll
            for (int mt = 1; mt < MT; ++mt) m = fmaxf(m, acc[mt][ot][rr]);
            if constexpr (TN == 4) m = fmaxf(m, __shfl_xor(m, 16));
            m = fmaxf(m, __shfl_xor(m, 32));
            v[rr] = m;
        }
        int o = (wv * OTW + ot) * 16 + (lane & 15);
        float s  = gp[o] * rsqrtf(vp[o] + EPS);
        float sh = bp[o] - mp[o] * s;
        bool valid = (TN == 8) ? (lane < 32) : (lane < 16);
        if (valid) {
            int lnb = (TN == 8) ? ((lane >> 4) << 2) : 0;
#pragma unroll
            for (int rr = 0; rr < 4; ++rr) {
                float h = fmaf(v[rr], s, sh);
                h = h > 0.f ? h : 0.2f * h;
                outBase[((size_t)b * N + n0 + lnb + rr) * 512 + o] = h;
            }
        }
    }
}

// ------------------------------------------------------------ global 512x512 MFMA (hi/lo), streaming K-loop
__global__ __launch_bounds__(256) void
global_mfma(const float* __restrict__ xcat,
            const unsigned short* __restrict__ Wh, const unsigned short* __restrict__ Wl,
            const float* __restrict__ gg, const float* __restrict__ bg,
            const float* __restrict__ mg, const float* __restrict__ vg,
            unsigned int* __restrict__ keys) {
    const int N = 2048, CV = 512;
    int b     = blockIdx.x & 7;
    int t     = blockIdx.x >> 3;
    int n0    = (t & 63) * 32;
    int colh  = t >> 6;
    int tid = threadIdx.x, lane = tid & 63, wv = tid >> 6;
    int obase = colh * 16 + wv * 4;

    f32x4 acc0[4], acc1[4];
#pragma unroll
    for (int ot = 0; ot < 4; ++ot)
#pragma unroll
        for (int rr = 0; rr < 4; ++rr) { acc0[ot][rr] = 0.f; acc1[ot][rr] = 0.f; }

    const float* arow0 = xcat + ((size_t)b * N + n0 +      (lane & 15)) * CV + ((lane >> 4) << 3);
    const float* arow1 = xcat + ((size_t)b * N + n0 + 16 + (lane & 15)) * CV + ((lane >> 4) << 3);

    for (int ks = 0; ks < 16; ++ks) {
        bf16x8 Ah0, Al0, Ah1, Al1;
        {
            float4 a  = *(const float4*)(arow0 + ks * 32);
            float4 b4 = *(const float4*)(arow0 + ks * 32 + 4);
            union { unsigned short u[8]; bf16x8 v; } ch, cl;
            hilo(a.x,  ch.u[0], cl.u[0]); hilo(a.y,  ch.u[1], cl.u[1]);
            hilo(a.z,  ch.u[2], cl.u[2]); hilo(a.w,  ch.u[3], cl.u[3]);
            hilo(b4.x, ch.u[4], cl.u[4]); hilo(b4.y, ch.u[5], cl.u[5]);
            hilo(b4.z, ch.u[6], cl.u[6]); hilo(b4.w, ch.u[7], cl.u[7]);
            Ah0 = ch.v; Al0 = cl.v;
        }
        {
            float4 a  = *(const float4*)(arow1 + ks * 32);
            float4 b4 = *(const float4*)(arow1 + ks * 32 + 4);
            union { unsigned short u[8]; bf16x8 v; } ch, cl;
            hilo(a.x,  ch.u[0], cl.u[0]); hilo(a.y,  ch.u[1], cl.u[1]);
            hilo(a.z,  ch.u[2], cl.u[2]); hilo(a.w,  ch.u[3], cl.u[3]);
            hilo(b4.x, ch.u[4], cl.u[4]); hilo(b4.y, ch.u[5], cl.u[5]);
            hilo(b4.z, ch.u[6], cl.u[6]); hilo(b4.w, ch.u[7], cl.u[7]);
            Ah1 = ch.v; Al1 = cl.v;
        }
#pragma unroll
        for (int ot = 0; ot < 4; ++ot) {
            size_t fi = (size_t)((((obase + ot) * 16 + ks) * 64 + lane)) << 3;
            bf16x8 Bh = *(const bf16x8*)(Wh + fi);
            bf16x8 Bl = *(const bf16x8*)(Wl + fi);
            acc0[ot] = __builtin_amdgcn_mfma_f32_16x16x32_bf16(Al0, Bh, acc0[ot], 0, 0, 0);
            acc0[ot] = __builtin_amdgcn_mfma_f32_16x16x32_bf16(Ah0, Bl, acc0[ot], 0, 0, 0);
            acc0[ot] = __builtin_amdgcn_mfma_f32_16x16x32_bf16(Ah0, Bh, acc0[ot], 0, 0, 0);
            acc1[ot] = __builtin_amdgcn_mfma_f32_16x16x32_bf16(Al1, Bh, acc1[ot], 0, 0, 0);
            acc1[ot] = __builtin_amdgcn_mfma_f32_16x16x32_bf16(Ah1, Bl, acc1[ot], 0, 0, 0);
            acc1[ot] = __builtin_amdgcn_mfma_f32_16x16x32_bf16(Ah1, Bh, acc1[ot], 0, 0, 0);
        }
    }

#pragma unroll
    for (int ot = 0; ot < 4; ++ot) {
        f32x4 v;
#pragma unroll
        for (int rr = 0; rr < 4; ++rr) {
            float m = fmaxf(acc0[ot][rr], acc1[ot][rr]);
            m = fmaxf(m, __shfl_xor(m, 16));
            m = fmaxf(m, __shfl_xor(m, 32));
            v[rr] = m;
        }
        int o = (obase + ot) * 16 + (lane & 15);
        float s  = gg[o] * rsqrtf(vg[o] + EPS);
        float sh = bg[o] - mg[o] * s;
        if (lane < 16) {
            float hm = -INFINITY;
#pragma unroll
            for (int rr = 0; rr < 4; ++rr) {
                float h = fmaf(v[rr], s, sh);
                h = h > 0.f ? h : 0.2f * h;
                hm = fmaxf(hm, h);
            }
            atomicMax(&keys[b * 512 + o], fkey(hm));
        }
    }
}

__global__ void decode_kernel(const unsigned int* __restrict__ keys, float* __restrict__ out) {
    int id = blockIdx.x * 256 + threadIdx.x;
    if (id < 8 * 512) out[id] = funkey(keys[id]);
}

// ---------------------------------------------------------------- launcher
extern "C" void kernel_launch(void* const* d_in, const int* in_sizes, int n_in,
                              void* d_out, int out_size, void* d_ws, size_t ws_size,
                              hipStream_t stream) {
    const int B = 8, N = 2048, K = 20;
    const float* pts = (const float*)d_in[0];
    const float* w1 = (const float*)d_in[1];
    const float *g1 = (const float*)d_in[2], *b1 = (const float*)d_in[3],
                *m1 = (const float*)d_in[4], *v1 = (const float*)d_in[5];
    const float* w2 = (const float*)d_in[6];
    const float *g2 = (const float*)d_in[7], *b2 = (const float*)d_in[8],
                *m2 = (const float*)d_in[9], *v2 = (const float*)d_in[10];
    const float* w3 = (const float*)d_in[11];
    const float *g3 = (const float*)d_in[12], *b3 = (const float*)d_in[13],
                *m3 = (const float*)d_in[14], *v3 = (const float*)d_in[15];
    const float* w4 = (const float*)d_in[16];
    const float *g4 = (const float*)d_in[17], *b4 = (const float*)d_in[18],
                *m4 = (const float*)d_in[19], *v4 = (const float*)d_in[20];
    const float* wg = (const float*)d_in[21];
    const float *gg = (const float*)d_in[22], *bg = (const float*)d_in[23],
                *mg = (const float*)d_in[24], *vg = (const float*)d_in[25];

    // workspace layout
    float* ws   = (float*)d_ws;
    float* xcat = ws;                                    // 8*2048*512 floats
    float* xx   = xcat + (size_t)B * N * 512;            // 8*2048
    int*   idx  = (int*)(xx + B * N);                    // 8*2048*20
    unsigned short* Fdh = (unsigned short*)(idx + (size_t)B * N * K);  // 8*2048*128 max
    unsigned short* Fdl = Fdh + (size_t)B * N * 128;
    unsigned short* wf1h = Fdl + (size_t)B * N * 128;
    unsigned short* wf1l = wf1h + 64 * 32;
    unsigned short* wf2h = wf1l + 64 * 32;
    unsigned short* wf2l = wf2h + 64 * 128;
    unsigned short* wf3h = wf2l + 64 * 128;
    unsigned short* wf3l = wf3h + 128 * 128;
    unsigned short* wf4h = wf3l + 128 * 128;
    unsigned short* wf4l = wf4h + 256 * 256;
    unsigned short* wfgh = wf4l + 256 * 256;
    unsigned short* wfgl = wfgh + 512 * 512;
    unsigned int* keys  = (unsigned int*)(wfgl + 512 * 512);

    // pack weight fragments (bf16 hi/lo)
    wfrag_kernel<<<(64 * 32 + 255) / 256, 256, 0, stream>>>(w1, 64, 6, 32, wf1h, wf1l);
    wfrag_kernel<<<(64 * 128 + 255) / 256, 256, 0, stream>>>(w2, 64, 128, 128, wf2h, wf2l);
    wfrag_kernel<<<(128 * 128 + 255) / 256, 256, 0, stream>>>(w3, 128, 128, 128, wf3h, wf3l);
    wfrag_kernel<<<(256 * 256 + 255) / 256, 256, 0, stream>>>(w4, 256, 256, 256, wf4h, wf4l);
    wfrag_kernel<<<(512 * 512 + 255) / 256, 256, 0, stream>>>(wg, 512, 512, 512, wfgh, wfgl);

    // ---- layer 1: C=3 -> 64, out offset 0
    xfrag_kernel<<<(8 * 128 * 1 * 512 + 255) / 256, 256, 0, stream>>>(pts, 3, 3, 1, Fdh, Fdl);
    sumsq_feat_kernel<<<(B * N + 255) / 256, 256, 0, stream>>>(pts, 3, 3, xx);
    dist_topk_mfma<32><<<B * (N / 16), 512, 0, stream>>>(Fdh, Fdl, xx, idx);
    edgeconv_mfma<3, 64, 8, 4, 1><<<B * (N / 8), 256, 0, stream>>>(pts, 3, idx, wf1h, wf1l, g1, b1, m1, v1, xcat + 0);

    // ---- layer 2: 64 -> 64, out offset 64
    xfrag_kernel<<<(8 * 128 * 2 * 512 + 255) / 256, 256, 0, stream>>>(xcat + 0, 512, 64, 2, Fdh, Fdl);
    sumsq_feat_kernel<<<(B * N + 255) / 256, 256, 0, stream>>>(xcat + 0, 512, 64, xx);
    dist_topk_mfma<64><<<B * (N / 16), 512, 0, stream>>>(Fdh, Fdl, xx, idx);
    edgeconv_mfma<64, 64, 4, 4, 1><<<B * (N / 4), 256, 0, stream>>>(xcat + 0, 512, idx, wf2h, wf2l, g2, b2, m2, v2, xcat + 64);

    // ---- layer 3: 64 -> 128, out offset 128
    xfrag_kernel<<<(8 * 128 * 2 * 512 + 255) / 256, 256, 0, stream>>>(xcat + 64, 512, 64, 2, Fdh, Fdl);
    sumsq_feat_kernel<<<(B * N + 255) / 256, 256, 0, stream>>>(xcat + 64, 512, 64, xx);
    dist_topk_mfma<64><<<B * (N / 16), 512, 0, stream>>>(Fdh, Fdl, xx, idx);
    edgeconv_mfma<64, 128, 4, 8, 1><<<B * (N / 4), 512, 0, stream>>>(xcat + 64, 512, idx, wf3h, wf3l, g3, b3, m3, v3, xcat + 128);

    // ---- layer 4: 128 -> 256, out offset 256 (K-chunked: NKC=2)
    xfrag_kernel<<<(8 * 128 * 4 * 512 + 255) / 256, 256, 0, stream>>>(xcat + 128, 512, 128, 4, Fdh, Fdl);
    sumsq_feat_kernel<<<(B * N + 255) / 256, 256, 0, stream>>>(xcat + 128, 512, 128, xx);
    dist_topk_mfma<128><<<B * (N / 16), 512, 0, stream>>>(Fdh, Fdl, xx, idx);
    edgeconv_mfma<128, 256, 4, 8, 2><<<B * (N / 4), 512, 0, stream>>>(xcat + 128, 512, idx, wf4h, wf4l, g4, b4, m4, v4, xcat + 256);

    // ---- global layer + max over N
    hipMemsetAsync(keys, 0, (size_t)B * 512 * sizeof(unsigned int), stream);
    global_mfma<<<B * 128, 256, 0, stream>>>(xcat, wfgh, wfgl, gg, bg, mg, vg, keys);
    decode_kernel<<<(B * 512 + 255) / 256, 256, 0, stream>>>(keys, (float*)d_out);
}

// Round 16
// 469.900 us; speedup vs baseline: 1.1487x; 1.0773x over previous
//
#include <hip/hip_runtime.h>
#include <hip/hip_bf16.h>

#define EPS 1e-5f

typedef __attribute__((ext_vector_type(8))) short bf16x8;
typedef __attribute__((ext_vector_type(4))) float f32x4;

// ---------------------------------------------------------------- utilities
__device__ __forceinline__ unsigned int fkey(float f) {
    unsigned int b = __float_as_uint(f);
    return (b & 0x80000000u) ? ~b : (b | 0x80000000u);
}
__device__ __forceinline__ float funkey(unsigned int k) {
    unsigned int b = (k & 0x80000000u) ? (k & 0x7fffffffu) : ~k;
    return __uint_as_float(b);
}
__device__ __forceinline__ unsigned short f2bu(float f) {
    union { __hip_bfloat16 h; unsigned short u; } cv;
    cv.h = __float2bfloat16(f);
    return cv.u;
}
__device__ __forceinline__ float bu2f(unsigned short u) {
    return __uint_as_float(((unsigned int)u) << 16);
}
__device__ __forceinline__ void hilo(float v, unsigned short& h, unsigned short& l) {
    h = f2bu(v);
    l = f2bu(v - bu2f(h));
}

// ------------------------------------------------------------ weight fragment packing (hi+lo, column window [coff, coff+CW))
__global__ void wfrag_kernel(const float* __restrict__ W, int CO, int CIN, int coff, int CW, int C2P,
                             unsigned short* __restrict__ Fh, unsigned short* __restrict__ Fl) {
    int id = blockIdx.x * 256 + threadIdx.x;
    int total = CO * C2P;
    if (id >= total) return;
    int j = id & 7, lane = (id >> 3) & 63, t = id >> 9;
    int KS = C2P >> 5;
    int ks = t % KS, ot = t / KS;
    int o = ot * 16 + (lane & 15);
    int c = ks * 32 + ((lane >> 4) << 3) + j;
    float v = (c < CW) ? W[o * CIN + coff + c] : 0.f;
    unsigned short h, l;
    hilo(v, h, l);
    Fh[id] = h;
    Fl[id] = l;
}

// ------------------------------------------------------------ feature fragment packing for gram/ctr MFMA
__global__ void xfrag_kernel(const float* __restrict__ feat, int fs, int C, int KS,
                             unsigned short* __restrict__ Fh, unsigned short* __restrict__ Fl) {
    const int N = 2048, NT = 128;
    int id = blockIdx.x * 256 + threadIdx.x;
    int total = 8 * NT * KS * 512;
    if (id >= total) return;
    int j = id & 7, lane = (id >> 3) & 63;
    int rest = id >> 9;
    int ks = rest % KS;
    int bt = rest / KS;
    int t = bt & 127, b = bt >> 7;
    int row = t * 16 + (lane & 15);
    int c = ks * 32 + ((lane >> 4) << 3) + j;
    float v = (c < C) ? feat[((size_t)(b * N + row)) * fs + c] : 0.f;
    unsigned short h, l;
    hilo(v, h, l);
    Fh[id] = h;
    Fl[id] = l;
}

// ------------------------------------------------------------ xx[b][n] = sum_c x^2 (row-major feat)
__global__ void sumsq_feat_kernel(const float* __restrict__ feat, int fs, int C,
                                  float* __restrict__ xx) {
    int id = blockIdx.x * 256 + threadIdx.x;
    if (id >= 8 * 2048) return;
    const float* p = feat + (size_t)id * fs;
    float s = 0.f;
    if ((C & 3) == 0) {
        for (int c = 0; c < C; c += 4) {
            float4 v = *(const float4*)(p + c);
            s = fmaf(v.x, v.x, s); s = fmaf(v.y, v.y, s);
            s = fmaf(v.z, v.z, s); s = fmaf(v.w, v.w, s);
        }
    } else {
        for (int c = 0; c < C; ++c) { float v = p[c]; s = fmaf(v, v, s); }
    }
    xx[id] = s;
}

// ------------------------------------------------------------ MFMA gram dist + exact top-20 (r15-validated)
template <int CP>
__global__ __launch_bounds__(512, 4) void
dist_topk_mfma(const unsigned short* __restrict__ Fh, const unsigned short* __restrict__ Fl,
               const float* __restrict__ xx, int* __restrict__ idxOut) {
    const int N = 2048, NT = 128, CAP = 448;
    constexpr int KS = CP / 32;
    int b  = blockIdx.x & 7;
    int mt = blockIdx.x >> 3;
    int tid = threadIdx.x, lane = tid & 63, wv = tid >> 6;

    __shared__ unsigned int gmax[16][64];
    __shared__ unsigned int Tsh[16];
    __shared__ unsigned int cnt[16];
    __shared__ unsigned long long cand[16][CAP];

    bf16x8 Ah[KS], Al[KS];
#pragma unroll
    for (int ks = 0; ks < KS; ++ks) {
        size_t fi = (((size_t)(b * NT + mt) * KS + ks) << 9) + (lane << 3);
        Ah[ks] = *(const bf16x8*)(Fh + fi);
        Al[ks] = *(const bf16x8*)(Fl + fi);
    }
    int rbase = (lane >> 4) << 2;
    float xxr[4];
#pragma unroll
    for (int rr = 0; rr < 4; ++rr) xxr[rr] = xx[b * N + mt * 16 + rbase + rr];

    auto gramkeys = [&](int ct, unsigned int* kout) {
        f32x4 acc;
#pragma unroll
        for (int rr = 0; rr < 4; ++rr) acc[rr] = 0.f;
#pragma unroll
        for (int ks = 0; ks < KS; ++ks) {
            size_t fi = (((size_t)(b * NT + ct) * KS + ks) << 9) + (lane << 3);
            bf16x8 Bh = *(const bf16x8*)(Fh + fi);
            bf16x8 Bl = *(const bf16x8*)(Fl + fi);
            acc = __builtin_amdgcn_mfma_f32_16x16x32_bf16(Al[ks], Bh, acc, 0, 0, 0);
            acc = __builtin_amdgcn_mfma_f32_16x16x32_bf16(Ah[ks], Bl, acc, 0, 0, 0);
            acc = __builtin_amdgcn_mfma_f32_16x16x32_bf16(Ah[ks], Bh, acc, 0, 0, 0);
        }
        float xxm = xx[b * N + ct * 16 + (lane & 15)];
#pragma unroll
        for (int rr = 0; rr < 4; ++rr)
            kout[rr] = fkey(2.f * acc[rr] - xxr[rr] - xxm);
    };

    unsigned int rmax0[4], rmax1[4];
#pragma unroll
    for (int rr = 0; rr < 4; ++rr) { rmax0[rr] = 0u; rmax1[rr] = 0u; }

    for (int i = 0; i < 8; ++i) {
        unsigned int kk[4];
        gramkeys(wv * 16 + i, kk);
#pragma unroll
        for (int rr = 0; rr < 4; ++rr) rmax0[rr] = rmax0[rr] > kk[rr] ? rmax0[rr] : kk[rr];
    }
    for (int i = 8; i < 16; ++i) {
        unsigned int kk[4];
        gramkeys(wv * 16 + i, kk);
#pragma unroll
        for (int rr = 0; rr < 4; ++rr) rmax1[rr] = rmax1[rr] > kk[rr] ? rmax1[rr] : kk[rr];
    }
#pragma unroll
    for (int s = 4; s <= 8; s <<= 1)
#pragma unroll
        for (int rr = 0; rr < 4; ++rr) {
            unsigned int o0 = (unsigned int)__shfl_xor((int)rmax0[rr], s);
            rmax0[rr] = rmax0[rr] > o0 ? rmax0[rr] : o0;
            unsigned int o1 = (unsigned int)__shfl_xor((int)rmax1[rr], s);
            rmax1[rr] = rmax1[rr] > o1 ? rmax1[rr] : o1;
        }
    if ((lane & 15) < 4) {
#pragma unroll
        for (int rr = 0; rr < 4; ++rr) {
            gmax[rbase + rr][wv * 8 + (lane & 3)]     = rmax0[rr];
            gmax[rbase + rr][wv * 8 + 4 + (lane & 3)] = rmax1[rr];
        }
    }
    __syncthreads();

#pragma unroll
    for (int pass = 0; pass < 2; ++pass) {
        int row = wv + 8 * pass;
        unsigned int S = gmax[row][lane];
#pragma unroll
        for (int k = 2; k <= 64; k <<= 1)
#pragma unroll
            for (int j2 = k >> 1; j2 > 0; j2 >>= 1) {
                unsigned int o = (unsigned int)__shfl_xor((int)S, j2);
                bool keepMax = (((lane & j2) == 0) == ((lane & k) == 0));
                unsigned int mx = S > o ? S : o;
                unsigned int mn = S > o ? o : S;
                S = keepMax ? mx : mn;
            }
        if (lane == 19) Tsh[row] = S;
        if (lane == 0) cnt[row] = 0u;
    }
    __syncthreads();

    for (int i = 0; i < 16; ++i) {
        int ct = wv * 16 + i;
        unsigned int kk[4];
        gramkeys(ct, kk);
        int m = ct * 16 + (lane & 15);
#pragma unroll
        for (int rr = 0; rr < 4; ++rr) {
            int row = rbase + rr;
            if (kk[rr] >= Tsh[row]) {
                unsigned int slot = atomicAdd(&cnt[row], 1u);
                if (slot < CAP)
                    cand[row][slot] = ((unsigned long long)kk[rr] << 16) |
                                      (unsigned long long)(0xFFFFu - (unsigned int)m);
            }
        }
    }
    __syncthreads();

#pragma unroll
    for (int pass = 0; pass < 2; ++pass) {
        int row = wv + 8 * pass;
        unsigned int nc = cnt[row];
        if (nc <= 64u) {
            unsigned long long P = (lane < (int)nc) ? cand[row][lane] : 0ULL;
#pragma unroll
            for (int k = 2; k <= 64; k <<= 1)
#pragma unroll
                for (int j2 = k >> 1; j2 > 0; j2 >>= 1) {
                    unsigned long long o = __shfl_xor(P, j2);
                    bool keepMax = (((lane & j2) == 0) == ((lane & k) == 0));
                    unsigned long long mx = P > o ? P : o;
                    unsigned long long mn = P > o ? o : P;
                    P = keepMax ? mx : mn;
                }
            if (lane < 20)
                idxOut[((size_t)b * N + mt * 16 + row) * 20 + lane] =
                    (int)(0xFFFFu - (unsigned int)(P & 0xFFFFu));
        } else {
            unsigned int ncc = nc < CAP ? nc : CAP;
            unsigned long long P0 = ((unsigned int)(lane)       < ncc) ? cand[row][lane]       : 0ULL;
            unsigned long long P1 = ((unsigned int)(lane + 64)  < ncc) ? cand[row][lane + 64]  : 0ULL;
            unsigned long long P2 = ((unsigned int)(lane + 128) < ncc) ? cand[row][lane + 128] : 0ULL;
            unsigned long long P3 = ((unsigned int)(lane + 192) < ncc) ? cand[row][lane + 192] : 0ULL;
            unsigned long long P4 = ((unsigned int)(lane + 256) < ncc) ? cand[row][lane + 256] : 0ULL;
            unsigned long long P5 = ((unsigned int)(lane + 320) < ncc) ? cand[row][lane + 320] : 0ULL;
            unsigned long long P6 = ((unsigned int)(lane + 384) < ncc) ? cand[row][lane + 384] : 0ULL;
            int resm = 0;
            for (int k = 0; k < 20; ++k) {
                unsigned long long lmx = P0;
                lmx = lmx > P1 ? lmx : P1;
                lmx = lmx > P2 ? lmx : P2;
                lmx = lmx > P3 ? lmx : P3;
                lmx = lmx > P4 ? lmx : P4;
                lmx = lmx > P5 ? lmx : P5;
                lmx = lmx > P6 ? lmx : P6;
#pragma unroll
                for (int s = 1; s < 64; s <<= 1) {
                    unsigned long long o = __shfl_xor(lmx, s);
                    lmx = lmx > o ? lmx : o;
                }
                P0 = (P0 == lmx) ? 0ULL : P0;
                P1 = (P1 == lmx) ? 0ULL : P1;
                P2 = (P2 == lmx) ? 0ULL : P2;
                P3 = (P3 == lmx) ? 0ULL : P3;
                P4 = (P4 == lmx) ? 0ULL : P4;
                P5 = (P5 == lmx) ? 0ULL : P5;
                P6 = (P6 == lmx) ? 0ULL : P6;
                if (lane == k) resm = (int)(0xFFFFu - (unsigned int)(lmx & 0xFFFFu));
            }
            if (lane < 20) idxOut[((size_t)b * N + mt * 16 + row) * 20 + lane] = resm;
        }
    }
}

// ------------------------------------------------------------ per-point center GEMM: ctrout[b][n][o] = Wc . x_n (hi/lo)
// consumes the dist feature fragments directly. grid = 8 * 128, 256 thr (4 waves).
template <int CP, int CO>
__global__ __launch_bounds__(256) void
ctr_mfma(const unsigned short* __restrict__ Fh, const unsigned short* __restrict__ Fl,
         const unsigned short* __restrict__ Wh, const unsigned short* __restrict__ Wl,
         float* __restrict__ out) {
    const int N = 2048, NT = 128;
    constexpr int KS = CP / 32;
    constexpr int OTW = CO / 64;      // otiles per wave (4 waves)
    int b  = blockIdx.x & 7;
    int mt = blockIdx.x >> 3;
    int tid = threadIdx.x, lane = tid & 63, wv = tid >> 6;

    bf16x8 Ah[KS], Al[KS];
#pragma unroll
    for (int ks = 0; ks < KS; ++ks) {
        size_t fi = (((size_t)(b * NT + mt) * KS + ks) << 9) + (lane << 3);
        Ah[ks] = *(const bf16x8*)(Fh + fi);
        Al[ks] = *(const bf16x8*)(Fl + fi);
    }
    int rbase = (lane >> 4) << 2;

    f32x4 acc[OTW];
#pragma unroll
    for (int ot = 0; ot < OTW; ++ot)
#pragma unroll
        for (int rr = 0; rr < 4; ++rr) acc[ot][rr] = 0.f;

#pragma unroll
    for (int ot = 0; ot < OTW; ++ot)
#pragma unroll
        for (int ks = 0; ks < KS; ++ks) {
            size_t fi = (size_t)((((wv * OTW + ot) * KS + ks) * 64 + lane)) << 3;
            bf16x8 Bh = *(const bf16x8*)(Wh + fi);
            bf16x8 Bl = *(const bf16x8*)(Wl + fi);
            acc[ot] = __builtin_amdgcn_mfma_f32_16x16x32_bf16(Al[ks], Bh, acc[ot], 0, 0, 0);
            acc[ot] = __builtin_amdgcn_mfma_f32_16x16x32_bf16(Ah[ks], Bl, acc[ot], 0, 0, 0);
            acc[ot] = __builtin_amdgcn_mfma_f32_16x16x32_bf16(Ah[ks], Bh, acc[ot], 0, 0, 0);
        }

#pragma unroll
    for (int ot = 0; ot < OTW; ++ot) {
        int o = (wv * OTW + ot) * 16 + (lane & 15);
#pragma unroll
        for (int rr = 0; rr < 4; ++rr)
            out[((size_t)(b * N + mt * 16 + rbase + rr)) * CO + o] = acc[ot][rr];
    }
}

// ------------------------------------------------------------ MFMA edgeconv over DIFF half only (K = CIP), + ctr after max
template <int CI, int CP, int CO, int TN, int WAVES>
__global__ __launch_bounds__(WAVES * 64) void
edgeconv_mfma(const float* __restrict__ feat, int fs, const int* __restrict__ idx,
              const unsigned short* __restrict__ Wh, const unsigned short* __restrict__ Wl,
              const float* __restrict__ ctrin,
              const float* __restrict__ gp, const float* __restrict__ bp,
              const float* __restrict__ mp, const float* __restrict__ vp,
              float* __restrict__ outBase) {
    constexpr int N = 2048, K = 20;
    constexpr int KS = CP / 32;
    constexpr int CHB = CP * 2;           // bytes per row
    constexpr int CH = CP / 8;            // uint4 groups per row
    constexpr int OT = CO / 16;
    constexpr int OTW = OT / WAVES;
    constexpr int M = TN * K;
    constexpr int MT = M / 16;
    constexpr int SWZ = (CHB / 16 - 1) > 15 ? 15 : (CHB / 16 - 1);
    constexpr int THREADS = WAVES * 64;

    int b  = blockIdx.x & 7;
    int n0 = (blockIdx.x >> 3) * TN;
    int tid = threadIdx.x;
    int lane = tid & 63, wv = tid >> 6;

    __shared__ float ctr[TN][CI];
    __shared__ int nb[M];
    __shared__ __align__(16) unsigned char Eh[M * CHB];
    __shared__ __align__(16) unsigned char El[M * CHB];

    for (int e = tid; e < TN * CI; e += THREADS) {
        int ln = e / CI, c = e % CI;
        ctr[ln][c] = feat[((size_t)b * N + n0 + ln) * fs + c];
    }
    for (int e = tid; e < M; e += THREADS) {
        int k = e / TN, ln = e % TN;
        nb[e] = idx[((size_t)b * N + n0 + ln) * K + k];
    }
    __syncthreads();

    // build swizzled bf16 DIFF matrix (hi+lo planes)
    for (int e = tid; e < M * CH; e += THREADS) {
        int mrow = e / CH, ch = e - mrow * CH;
        int c0 = ch * 8;
        int ln = mrow % TN;
        float v[8];
        if constexpr (CI >= 8) {
            const float* nrow = feat + ((size_t)b * N + nb[mrow]) * fs + c0;
            float4 a  = *(const float4*)nrow;
            float4 b4 = *(const float4*)(nrow + 4);
            v[0] = a.x  - ctr[ln][c0 + 0];
            v[1] = a.y  - ctr[ln][c0 + 1];
            v[2] = a.z  - ctr[ln][c0 + 2];
            v[3] = a.w  - ctr[ln][c0 + 3];
            v[4] = b4.x - ctr[ln][c0 + 4];
            v[5] = b4.y - ctr[ln][c0 + 5];
            v[6] = b4.z - ctr[ln][c0 + 6];
            v[7] = b4.w - ctr[ln][c0 + 7];
        } else {  // CI == 3
            if (c0 == 0) {
                const float* nrow = feat + ((size_t)b * N + nb[mrow]) * fs;
                v[0] = nrow[0] - ctr[ln][0];
                v[1] = nrow[1] - ctr[ln][1];
                v[2] = nrow[2] - ctr[ln][2];
                v[3] = 0.f; v[4] = 0.f; v[5] = 0.f; v[6] = 0.f; v[7] = 0.f;
            } else {
#pragma unroll
                for (int j = 0; j < 8; ++j) v[j] = 0.f;
            }
        }
        union { unsigned short u[8]; uint4 v4; } th, tl;
#pragma unroll
        for (int j = 0; j < 8; ++j) hilo(v[j], th.u[j], tl.u[j]);
        int off = mrow * CHB + ((ch * 16) ^ ((mrow & SWZ) << 4));
        *(uint4*)&Eh[off] = th.v4;
        *(uint4*)&El[off] = tl.v4;
    }
    __syncthreads();

    bf16x8 Bh[OTW][KS], Bl[OTW][KS];
#pragma unroll
    for (int ot = 0; ot < OTW; ++ot)
#pragma unroll
        for (int ks = 0; ks < KS; ++ks) {
            size_t fi = (size_t)((((wv * OTW + ot) * KS + ks) * 64 + lane)) << 3;
            Bh[ot][ks] = *(const bf16x8*)(Wh + fi);
            Bl[ot][ks] = *(const bf16x8*)(Wl + fi);
        }

    f32x4 acc[MT][OTW];
#pragma unroll
    for (int mt = 0; mt < MT; ++mt)
#pragma unroll
        for (int ot = 0; ot < OTW; ++ot)
#pragma unroll
            for (int rr = 0; rr < 4; ++rr) acc[mt][ot][rr] = 0.f;

#pragma unroll
    for (int mt = 0; mt < MT; ++mt) {
        int r0 = mt * 16 + (lane & 15);
        int cb = (lane >> 4) << 4;
        bf16x8 Ah[KS], Al[KS];
#pragma unroll
        for (int ks = 0; ks < KS; ++ks) {
            int off = r0 * CHB + (((ks << 6) + cb) ^ ((r0 & SWZ) << 4));
            Ah[ks] = *(const bf16x8*)&Eh[off];
            Al[ks] = *(const bf16x8*)&El[off];
        }
#pragma unroll
        for (int ks = 0; ks < KS; ++ks)
#pragma unroll
            for (int ot = 0; ot < OTW; ++ot) {
                acc[mt][ot] = __builtin_amdgcn_mfma_f32_16x16x32_bf16(Al[ks], Bh[ot][ks], acc[mt][ot], 0, 0, 0);
                acc[mt][ot] = __builtin_amdgcn_mfma_f32_16x16x32_bf16(Ah[ks], Bl[ot][ks], acc[mt][ot], 0, 0, 0);
                acc[mt][ot] = __builtin_amdgcn_mfma_f32_16x16x32_bf16(Ah[ks], Bh[ot][ks], acc[mt][ot], 0, 0, 0);
            }
    }

#pragma unroll
    for (int ot = 0; ot < OTW; ++ot) {
        f32x4 v;
#pragma unroll
        for (int rr = 0; rr < 4; ++rr) {
            float m = acc[0][ot][rr];
#pragma unroll
            for (int mt = 1; mt < MT; ++mt) m = fmaxf(m, acc[mt][ot][rr]);
            if constexpr (TN == 4) m = fmaxf(m, __shfl_xor(m, 16));
            m = fmaxf(m, __shfl_xor(m, 32));
            v[rr] = m;
        }
        int o = (wv * OTW + ot) * 16 + (lane & 15);
        float s  = gp[o] * rsqrtf(vp[o] + EPS);
        float sh = bp[o] - mp[o] * s;
        bool valid = (TN == 8) ? (lane < 32) : (lane < 16);
        if (valid) {
            int lnb = (TN == 8) ? ((lane >> 4) << 2) : 0;
#pragma unroll
            for (int rr = 0; rr < 4; ++rr) {
                float c = ctrin[((size_t)(b * N + n0 + lnb + rr)) * CO + o];
                float h = fmaf(v[rr] + c, s, sh);
                h = h > 0.f ? h : 0.2f * h;
                outBase[((size_t)b * N + n0 + lnb + rr) * 512 + o] = h;
            }
        }
    }
}

// ------------------------------------------------------------ global 512x512 MFMA (hi/lo), streaming K-loop
__global__ __launch_bounds__(256) void
global_mfma(const float* __restrict__ xcat,
            const unsigned short* __restrict__ Wh, const unsigned short* __restrict__ Wl,
            const float* __restrict__ gg, const float* __restrict__ bg,
            const float* __restrict__ mg, const float* __restrict__ vg,
            unsigned int* __restrict__ keys) {
    const int N = 2048, CV = 512;
    int b     = blockIdx.x & 7;
    int t     = blockIdx.x >> 3;
    int n0    = (t & 63) * 32;
    int colh  = t >> 6;
    int tid = threadIdx.x, lane = tid & 63, wv = tid >> 6;
    int obase = colh * 16 + wv * 4;

    f32x4 acc0[4], acc1[4];
#pragma unroll
    for (int ot = 0; ot < 4; ++ot)
#pragma unroll
        for (int rr = 0; rr < 4; ++rr) { acc0[ot][rr] = 0.f; acc1[ot][rr] = 0.f; }

    const float* arow0 = xcat + ((size_t)b * N + n0 +      (lane & 15)) * CV + ((lane >> 4) << 3);
    const float* arow1 = xcat + ((size_t)b * N + n0 + 16 + (lane & 15)) * CV + ((lane >> 4) << 3);

    for (int ks = 0; ks < 16; ++ks) {
        bf16x8 Ah0, Al0, Ah1, Al1;
        {
            float4 a  = *(const float4*)(arow0 + ks * 32);
            float4 b4 = *(const float4*)(arow0 + ks * 32 + 4);
            union { unsigned short u[8]; bf16x8 v; } ch, cl;
            hilo(a.x,  ch.u[0], cl.u[0]); hilo(a.y,  ch.u[1], cl.u[1]);
            hilo(a.z,  ch.u[2], cl.u[2]); hilo(a.w,  ch.u[3], cl.u[3]);
            hilo(b4.x, ch.u[4], cl.u[4]); hilo(b4.y, ch.u[5], cl.u[5]);
            hilo(b4.z, ch.u[6], cl.u[6]); hilo(b4.w, ch.u[7], cl.u[7]);
            Ah0 = ch.v; Al0 = cl.v;
        }
        {
            float4 a  = *(const float4*)(arow1 + ks * 32);
            float4 b4 = *(const float4*)(arow1 + ks * 32 + 4);
            union { unsigned short u[8]; bf16x8 v; } ch, cl;
            hilo(a.x,  ch.u[0], cl.u[0]); hilo(a.y,  ch.u[1], cl.u[1]);
            hilo(a.z,  ch.u[2], cl.u[2]); hilo(a.w,  ch.u[3], cl.u[3]);
            hilo(b4.x, ch.u[4], cl.u[4]); hilo(b4.y, ch.u[5], cl.u[5]);
            hilo(b4.z, ch.u[6], cl.u[6]); hilo(b4.w, ch.u[7], cl.u[7]);
            Ah1 = ch.v; Al1 = cl.v;
        }
#pragma unroll
        for (int ot = 0; ot < 4; ++ot) {
            size_t fi = (size_t)((((obase + ot) * 16 + ks) * 64 + lane)) << 3;
            bf16x8 Bh = *(const bf16x8*)(Wh + fi);
            bf16x8 Bl = *(const bf16x8*)(Wl + fi);
            acc0[ot] = __builtin_amdgcn_mfma_f32_16x16x32_bf16(Al0, Bh, acc0[ot], 0, 0, 0);
            acc0[ot] = __builtin_amdgcn_mfma_f32_16x16x32_bf16(Ah0, Bl, acc0[ot], 0, 0, 0);
            acc0[ot] = __builtin_amdgcn_mfma_f32_16x16x32_bf16(Ah0, Bh, acc0[ot], 0, 0, 0);
            acc1[ot] = __builtin_amdgcn_mfma_f32_16x16x32_bf16(Al1, Bh, acc1[ot], 0, 0, 0);
            acc1[ot] = __builtin_amdgcn_mfma_f32_16x16x32_bf16(Ah1, Bl, acc1[ot], 0, 0, 0);
            acc1[ot] = __builtin_amdgcn_mfma_f32_16x16x32_bf16(Ah1, Bh, acc1[ot], 0, 0, 0);
        }
    }

#pragma unroll
    for (int ot = 0; ot < 4; ++ot) {
        f32x4 v;
#pragma unroll
        for (int rr = 0; rr < 4; ++rr) {
            float m = fmaxf(acc0[ot][rr], acc1[ot][rr]);
            m = fmaxf(m, __shfl_xor(m, 16));
            m = fmaxf(m, __shfl_xor(m, 32));
            v[rr] = m;
        }
        int o = (obase + ot) * 16 + (lane & 15);
        float s  = gg[o] * rsqrtf(vg[o] + EPS);
        float sh = bg[o] - mg[o] * s;
        if (lane < 16) {
            float hm = -INFINITY;
#pragma unroll
            for (int rr = 0; rr < 4; ++rr) {
                float h = fmaf(v[rr], s, sh);
                h = h > 0.f ? h : 0.2f * h;
                hm = fmaxf(hm, h);
            }
            atomicMax(&keys[b * 512 + o], fkey(hm));
        }
    }
}

__global__ void decode_kernel(const unsigned int* __restrict__ keys, float* __restrict__ out) {
    int id = blockIdx.x * 256 + threadIdx.x;
    if (id < 8 * 512) out[id] = funkey(keys[id]);
}

// ---------------------------------------------------------------- launcher
extern "C" void kernel_launch(void* const* d_in, const int* in_sizes, int n_in,
                              void* d_out, int out_size, void* d_ws, size_t ws_size,
                              hipStream_t stream) {
    const int B = 8, N = 2048, K = 20;
    const float* pts = (const float*)d_in[0];
    const float* w1 = (const float*)d_in[1];
    const float *g1 = (const float*)d_in[2], *b1 = (const float*)d_in[3],
                *m1 = (const float*)d_in[4], *v1 = (const float*)d_in[5];
    const float* w2 = (const float*)d_in[6];
    const float *g2 = (const float*)d_in[7], *b2 = (const float*)d_in[8],
                *m2 = (const float*)d_in[9], *v2 = (const float*)d_in[10];
    const float* w3 = (const float*)d_in[11];
    const float *g3 = (const float*)d_in[12], *b3 = (const float*)d_in[13],
                *m3 = (const float*)d_in[14], *v3 = (const float*)d_in[15];
    const float* w4 = (const float*)d_in[16];
    const float *g4 = (const float*)d_in[17], *b4 = (const float*)d_in[18],
                *m4 = (const float*)d_in[19], *v4 = (const float*)d_in[20];
    const float* wg = (const float*)d_in[21];
    const float *gg = (const float*)d_in[22], *bg = (const float*)d_in[23],
                *mg = (const float*)d_in[24], *vg = (const float*)d_in[25];

    // workspace layout
    float* ws   = (float*)d_ws;
    float* xcat = ws;                                    // 8*2048*512 floats
    float* xx   = xcat + (size_t)B * N * 512;            // 8*2048
    float* ctro = xx + (size_t)B * N;                    // 8*2048*256 floats
    int*   idx  = (int*)(ctro + (size_t)B * N * 256);    // 8*2048*20
    unsigned short* Fdh = (unsigned short*)(idx + (size_t)B * N * K);  // 8*2048*128
    unsigned short* Fdl = Fdh + (size_t)B * N * 128;
    unsigned short* wc1h = Fdl + (size_t)B * N * 128;
    unsigned short* wc1l = wc1h + 64 * 32;
    unsigned short* wd1h = wc1l + 64 * 32;
    unsigned short* wd1l = wd1h + 64 * 32;
    unsigned short* wc2h = wd1l + 64 * 32;
    unsigned short* wc2l = wc2h + 64 * 64;
    unsigned short* wd2h = wc2l + 64 * 64;
    unsigned short* wd2l = wd2h + 64 * 64;
    unsigned short* wc3h = wd2l + 64 * 64;
    unsigned short* wc3l = wc3h + 128 * 64;
    unsigned short* wd3h = wc3l + 128 * 64;
    unsigned short* wd3l = wd3h + 128 * 64;
    unsigned short* wc4h = wd3l + 128 * 64;
    unsigned short* wc4l = wc4h + 256 * 128;
    unsigned short* wd4h = wc4l + 256 * 128;
    unsigned short* wd4l = wd4h + 256 * 128;
    unsigned short* wfgh = wd4l + 256 * 128;
    unsigned short* wfgl = wfgh + 512 * 512;
    unsigned int* keys  = (unsigned int*)(wfgl + 512 * 512);

    // pack weight fragments (bf16 hi/lo): center half (Wc) and diff half (Wd)
    wfrag_kernel<<<(64 * 32 + 255) / 256, 256, 0, stream>>>(w1, 64, 6, 0, 3, 32, wc1h, wc1l);
    wfrag_kernel<<<(64 * 32 + 255) / 256, 256, 0, stream>>>(w1, 64, 6, 3, 3, 32, wd1h, wd1l);
    wfrag_kernel<<<(64 * 64 + 255) / 256, 256, 0, stream>>>(w2, 64, 128, 0, 64, 64, wc2h, wc2l);
    wfrag_kernel<<<(64 * 64 + 255) / 256, 256, 0, stream>>>(w2, 64, 128, 64, 64, 64, wd2h, wd2l);
    wfrag_kernel<<<(128 * 64 + 255) / 256, 256, 0, stream>>>(w3, 128, 128, 0, 64, 64, wc3h, wc3l);
    wfrag_kernel<<<(128 * 64 + 255) / 256, 256, 0, stream>>>(w3, 128, 128, 64, 64, 64, wd3h, wd3l);
    wfrag_kernel<<<(256 * 128 + 255) / 256, 256, 0, stream>>>(w4, 256, 256, 0, 128, 128, wc4h, wc4l);
    wfrag_kernel<<<(256 * 128 + 255) / 256, 256, 0, stream>>>(w4, 256, 256, 128, 128, 128, wd4h, wd4l);
    wfrag_kernel<<<(512 * 512 + 255) / 256, 256, 0, stream>>>(wg, 512, 512, 0, 512, 512, wfgh, wfgl);

    // ---- layer 1: C=3 -> 64, out offset 0
    xfrag_kernel<<<(8 * 128 * 1 * 512 + 255) / 256, 256, 0, stream>>>(pts, 3, 3, 1, Fdh, Fdl);
    sumsq_feat_kernel<<<(B * N + 255) / 256, 256, 0, stream>>>(pts, 3, 3, xx);
    dist_topk_mfma<32><<<B * (N / 16), 512, 0, stream>>>(Fdh, Fdl, xx, idx);
    ctr_mfma<32, 64><<<B * 128, 256, 0, stream>>>(Fdh, Fdl, wc1h, wc1l, ctro);
    edgeconv_mfma<3, 32, 64, 8, 4><<<B * (N / 8), 256, 0, stream>>>(pts, 3, idx, wd1h, wd1l, ctro, g1, b1, m1, v1, xcat + 0);

    // ---- layer 2: 64 -> 64, out offset 64
    xfrag_kernel<<<(8 * 128 * 2 * 512 + 255) / 256, 256, 0, stream>>>(xcat + 0, 512, 64, 2, Fdh, Fdl);
    sumsq_feat_kernel<<<(B * N + 255) / 256, 256, 0, stream>>>(xcat + 0, 512, 64, xx);
    dist_topk_mfma<64><<<B * (N / 16), 512, 0, stream>>>(Fdh, Fdl, xx, idx);
    ctr_mfma<64, 64><<<B * 128, 256, 0, stream>>>(Fdh, Fdl, wc2h, wc2l, ctro);
    edgeconv_mfma<64, 64, 64, 4, 4><<<B * (N / 4), 256, 0, stream>>>(xcat + 0, 512, idx, wd2h, wd2l, ctro, g2, b2, m2, v2, xcat + 64);

    // ---- layer 3: 64 -> 128, out offset 128
    xfrag_kernel<<<(8 * 128 * 2 * 512 + 255) / 256, 256, 0, stream>>>(xcat + 64, 512, 64, 2, Fdh, Fdl);
    sumsq_feat_kernel<<<(B * N + 255) / 256, 256, 0, stream>>>(xcat + 64, 512, 64, xx);
    dist_topk_mfma<64><<<B * (N / 16), 512, 0, stream>>>(Fdh, Fdl, xx, idx);
    ctr_mfma<64, 128><<<B * 128, 256, 0, stream>>>(Fdh, Fdl, wc3h, wc3l, ctro);
    edgeconv_mfma<64, 64, 128, 4, 8><<<B * (N / 4), 512, 0, stream>>>(xcat + 64, 512, idx, wd3h, wd3l, ctro, g3, b3, m3, v3, xcat + 128);

    // ---- layer 4: 128 -> 256, out offset 256
    xfrag_kernel<<<(8 * 128 * 4 * 512 + 255) / 256, 256, 0, stream>>>(xcat + 128, 512, 128, 4, Fdh, Fdl);
    sumsq_feat_kernel<<<(B * N + 255) / 256, 256, 0, stream>>>(xcat + 128, 512, 128, xx);
    dist_topk_mfma<128><<<B * (N / 16), 512, 0, stream>>>(Fdh, Fdl, xx, idx);
    ctr_mfma<128, 256><<<B * 128, 256, 0, stream>>>(Fdh, Fdl, wc4h, wc4l, ctro);
    edgeconv_mfma<128, 128, 256, 4, 8><<<B * (N / 4), 512, 0, stream>>>(xcat + 128, 512, idx, wd4h, wd4l, ctro, g4, b4, m4, v4, xcat + 256);

    // ---- global layer + max over N
    hipMemsetAsync(keys, 0, (size_t)B * 512 * sizeof(unsigned int), stream);
    global_mfma<<<B * 128, 256, 0, stream>>>(xcat, wfgh, wfgl, gg, bg, mg, vg, keys);
    decode_kernel<<<(B * 512 + 255) / 256, 256, 0, stream>>>(keys, (float*)d_out);
}